// Round 10
// baseline (280.853 us; speedup 1.0000x reference)
//
#include <hip/hip_runtime.h>

#define T_TOK 2048
#define DIM   512
#define MOE   256
#define NE    64
#define NG    8
#define TOPKG 4
#define TOPK  8
#define CAP   1024
#define MOE_SCALE 2.5f

typedef float f32x4 __attribute__((ext_vector_type(4)));
typedef short s16x8 __attribute__((ext_vector_type(8)));

__device__ __forceinline__ unsigned short f2bf(float f) {
    unsigned u = __builtin_bit_cast(unsigned, f);
    unsigned r = (u + 0x7fffu + ((u >> 16) & 1u)) >> 16;
    return (unsigned short)r;
}
__device__ __forceinline__ unsigned pk2(float lo, float hi) {
    return (unsigned)f2bf(lo) | ((unsigned)f2bf(hi) << 16);
}

// ---------------- gw transpose ------------------------------------------------
__global__ __launch_bounds__(256) void gwt_k(const float* __restrict__ gw,
                                             float* __restrict__ gwT)
{
    int idx = blockIdx.x * 256 + threadIdx.x;
    int e = idx >> 9, k = idx & 511;
    gwT[(size_t)(k >> 2) * 256 + e * 4 + (k & 3)] = gw[idx];
}

// ---------------- Fused gating + x->bf16, one wave per token ------------------
__global__ __launch_bounds__(256) void gate_fused_k(const float* __restrict__ x,
                                                    const float* __restrict__ gwT,
                                                    const float* __restrict__ gb,
                                                    int* __restrict__ counts,
                                                    int* __restrict__ etok,
                                                    float* __restrict__ wt_of,
                                                    short* __restrict__ xb)
{
    __shared__ float xs[4][512];
    int w = threadIdx.x >> 6, lane = threadIdx.x & 63;
    int t = blockIdx.x * 4 + w;

    {
        const float4* xr = (const float4*)(x + (size_t)t * DIM);
        float4 v0 = xr[lane * 2], v1 = xr[lane * 2 + 1];
        *(float4*)&xs[w][lane * 8]     = v0;
        *(float4*)&xs[w][lane * 8 + 4] = v1;
        short o[8];
        o[0] = (short)f2bf(v0.x); o[1] = (short)f2bf(v0.y);
        o[2] = (short)f2bf(v0.z); o[3] = (short)f2bf(v0.w);
        o[4] = (short)f2bf(v1.x); o[5] = (short)f2bf(v1.y);
        o[6] = (short)f2bf(v1.z); o[7] = (short)f2bf(v1.w);
        *(s16x8*)(xb + (size_t)t * DIM + lane * 8) = *(const s16x8*)o;
    }
    __syncthreads();

    const float4* gt = (const float4*)gwT;
    float a0 = 0.f, a1 = 0.f, a2 = 0.f, a3 = 0.f;
#pragma unroll 4
    for (int k4 = 0; k4 < 128; k4 += 4) {
        float4 g0 = gt[(k4 + 0) * 64 + lane];
        float4 g1 = gt[(k4 + 1) * 64 + lane];
        float4 g2 = gt[(k4 + 2) * 64 + lane];
        float4 g3 = gt[(k4 + 3) * 64 + lane];
        float4 x0 = *(const float4*)&xs[w][(k4 + 0) * 4];
        float4 x1 = *(const float4*)&xs[w][(k4 + 1) * 4];
        float4 x2 = *(const float4*)&xs[w][(k4 + 2) * 4];
        float4 x3 = *(const float4*)&xs[w][(k4 + 3) * 4];
        a0 += g0.x * x0.x + g0.y * x0.y + g0.z * x0.z + g0.w * x0.w;
        a1 += g1.x * x1.x + g1.y * x1.y + g1.z * x1.z + g1.w * x1.w;
        a2 += g2.x * x2.x + g2.y * x2.y + g2.z * x2.z + g2.w * x2.w;
        a3 += g3.x * x3.x + g3.y * x3.y + g3.z * x3.z + g3.w * x3.w;
    }
    float acc = (a0 + a1) + (a2 + a3);
    float sc = 1.f / (1.f + __expf(-acc));
    float s  = sc + gb[lane];

    float m1 = s, m2 = -1e30f;
#pragma unroll
    for (int d = 1; d < 8; d <<= 1) {
        float o1 = __shfl_xor(m1, d);
        float o2 = __shfl_xor(m2, d);
        float n1 = fmaxf(m1, o1);
        float n2 = fmaxf(fminf(m1, o1), fmaxf(m2, o2));
        m1 = n1; m2 = n2;
    }
    float gv = m1 + m2;

    bool gkeep = false;
#pragma unroll
    for (int it = 0; it < TOPKG; ++it) {
        float m = gv;
#pragma unroll
        for (int d = 1; d < 64; d <<= 1) m = fmaxf(m, __shfl_xor(m, d));
        unsigned long long mask = __ballot(gv == m);
        int ldr = __ffsll(mask) - 1;
        if ((lane >> 3) == (ldr >> 3)) { gkeep = true; gv = -2e30f; }
    }
    float sv = gkeep ? s : -1e30f;

    float wsum = 0.f;
    int my_e = 0; float my_w = 0.f;
#pragma unroll
    for (int k = 0; k < TOPK; ++k) {
        float m = sv;
#pragma unroll
        for (int d = 1; d < 64; d <<= 1) m = fmaxf(m, __shfl_xor(m, d));
        unsigned long long mask = __ballot(sv == m);
        int l = __ffsll(mask) - 1;
        float wk = __shfl(sc, l);
        wsum += wk;
        if (lane == k) { my_e = l; my_w = wk; }
        if (lane == l) sv = -2e30f;
    }
    float scale = MOE_SCALE / wsum;
    if (lane < TOPK) {
        int p = atomicAdd(&counts[my_e], 1);
        int rid = t * TOPK + lane;
        bool ok = (p < CAP);
        if (ok) etok[my_e * CAP + p] = rid;
        wt_of[rid] = ok ? my_w * scale : 0.f;
    }
}

// ---------------- scan: tile-base per expert (pad-to-32) ----------------------
__global__ __launch_bounds__(64) void scan_k(const int* __restrict__ counts,
                                             int* __restrict__ tbase)
{
    int lane = threadIdx.x;
    int ne = min(counts[lane], CAP);
    int nt = (ne + 31) >> 5;
    int v = nt;
#pragma unroll
    for (int d = 1; d < 64; d <<= 1) {
        int o = __shfl_up(v, d);
        if (lane >= d) v += o;
    }
    tbase[lane] = v - nt;
}

// ---------------- gather: tokens -> xg in A-frag-major layout -----------------
__global__ __launch_bounds__(256, 4) void gather_k(const short* __restrict__ xb,
                                                   const int* __restrict__ counts,
                                                   const int* __restrict__ etok,
                                                   const int* __restrict__ tbase,
                                                   short* __restrict__ xgf)
{
    int e = blockIdx.x >> 3, sub3 = blockIdx.x & 7;
    int w = threadIdx.x >> 6, lane = threadIdx.x & 63;
    int T = sub3 * 4 + w;
    int ne = min(counts[e], CAP);
    int nt = (ne + 31) >> 5;
    if (T >= nt) return;
    int G = tbase[e] + T;
    int q = lane >> 4, m16 = lane & 15;
    int r0 = T * 32 + m16, r1 = T * 32 + 16 + m16;
    bool ok0 = r0 < ne, ok1 = r1 < ne;
    int tok0 = ok0 ? (etok[e * CAP + r0] >> 3) : 0;
    int tok1 = ok1 ? (etok[e * CAP + r1] >> 3) : 0;
    const short* s0 = xb + (size_t)tok0 * DIM + q * 8;
    const short* s1 = xb + (size_t)tok1 * DIM + q * 8;
    short* dst = xgf + (size_t)G * 16384 + lane * 8;
    s16x8 z = {0, 0, 0, 0, 0, 0, 0, 0};
    // batch 8 loads, then 8 stores (deep MLP)
#pragma unroll
    for (int b4 = 0; b4 < 4; ++b4) {
        s16x8 v[8];
#pragma unroll
        for (int i = 0; i < 4; ++i) {
            int kt = b4 * 4 + i;
            v[i * 2]     = ok0 ? *(const s16x8*)(s0 + kt * 32) : z;
            v[i * 2 + 1] = ok1 ? *(const s16x8*)(s1 + kt * 32) : z;
        }
#pragma unroll
        for (int i = 0; i < 4; ++i) {
            int kt = b4 * 4 + i;
            *(s16x8*)(dst + (size_t)(kt * 2 + 0) * 512) = v[i * 2];
            *(s16x8*)(dst + (size_t)(kt * 2 + 1) * 512) = v[i * 2 + 1];
        }
    }
}

// ---------------- K1: h = silu(X@W1)*(X@W3) ----------------------------------
// Block = (expert, 16-col slice), 1024 blocks, 32 KB B-LDS, acc = 32 VGPR.
// Each wave processes TWO tiles per iteration (independent A-chains).
__global__ __launch_bounds__(256, 4) void gemm1_k(const short* __restrict__ xgf,
                                                  const float* __restrict__ w1,
                                                  const float* __restrict__ w3,
                                                  const int* __restrict__ counts,
                                                  const int* __restrict__ tbase,
                                                  short* __restrict__ hgf)
{
    __shared__ short Bl[2][16][64][8];       // mat, kt, flane, j = 32 KB
    __shared__ short Ct[4][2][16][24];       // wave, sub, row, col(+pad) = 6 KB

    int e  = blockIdx.x & 63, cg = blockIdx.x >> 6;   // cg 0..15 -> 16-col slice
    int n0 = cg * 16;
    int tid = threadIdx.x;
    int w = tid >> 6, lane = tid & 63;
    int q = lane >> 4, m16 = lane & 15;

    // ---- stage W1/W3 slice: 2048 (mat, row-pair, col-quad) items, 8/thread ----
    const float* W1e = w1 + (size_t)e * DIM * MOE + n0;
    const float* W3e = w3 + (size_t)e * DIM * MOE + n0;
#pragma unroll
    for (int it = 0; it < 8; ++it) {
        int idx = it * 256 + tid;
        int mat = idx >> 10;
        int rem = idx & 1023;
        int r2  = rem >> 2;              // row pair 0..255
        int cq  = (rem & 3) * 4;         // col 0,4,8,12
        int k   = r2 * 2;
        int kt = k >> 5, qf = (k >> 3) & 3, j0 = k & 7;
        const float* p = (mat ? W3e : W1e) + (size_t)k * MOE + cq;
        float4 lo = *(const float4*)p;
        float4 hi = *(const float4*)(p + MOE);
        unsigned* b = (unsigned*)&Bl[mat][kt][qf * 16 + cq][j0];
        b[0]  = pk2(lo.x, hi.x);
        b[4]  = pk2(lo.y, hi.y);
        b[8]  = pk2(lo.z, hi.z);
        b[12] = pk2(lo.w, hi.w);
    }
    __syncthreads();

    int ne = min(counts[e], CAP);
    int nt = (ne + 31) >> 5;
    int G0 = tbase[e];

    for (int T0 = w * 2; T0 < nt; T0 += 8) {
        bool v1 = (T0 + 1) < nt;
        const short* A0 = xgf + (size_t)(G0 + T0) * 16384 + lane * 8;
        const short* A1 = xgf + (size_t)(G0 + (v1 ? T0 + 1 : T0)) * 16384 + lane * 8;

        f32x4 acc[2][2][2];   // [tile][sub][mat]
#pragma unroll
        for (int i = 0; i < 2; ++i)
#pragma unroll
            for (int j = 0; j < 2; ++j)
#pragma unroll
                for (int m = 0; m < 2; ++m) acc[i][j][m] = (f32x4)0.f;

#pragma unroll
        for (int kt = 0; kt < 16; ++kt) {
            s16x8 a00 = *(const s16x8*)(A0 + (size_t)(kt * 2 + 0) * 512);
            s16x8 a01 = *(const s16x8*)(A0 + (size_t)(kt * 2 + 1) * 512);
            s16x8 a10 = *(const s16x8*)(A1 + (size_t)(kt * 2 + 0) * 512);
            s16x8 a11 = *(const s16x8*)(A1 + (size_t)(kt * 2 + 1) * 512);
            s16x8 b1 = *(const s16x8*)&Bl[0][kt][lane][0];
            s16x8 b3 = *(const s16x8*)&Bl[1][kt][lane][0];
            acc[0][0][0] = __builtin_amdgcn_mfma_f32_16x16x32_bf16(a00, b1, acc[0][0][0], 0, 0, 0);
            acc[0][1][0] = __builtin_amdgcn_mfma_f32_16x16x32_bf16(a01, b1, acc[0][1][0], 0, 0, 0);
            acc[1][0][0] = __builtin_amdgcn_mfma_f32_16x16x32_bf16(a10, b1, acc[1][0][0], 0, 0, 0);
            acc[1][1][0] = __builtin_amdgcn_mfma_f32_16x16x32_bf16(a11, b1, acc[1][1][0], 0, 0, 0);
            acc[0][0][1] = __builtin_amdgcn_mfma_f32_16x16x32_bf16(a00, b3, acc[0][0][1], 0, 0, 0);
            acc[0][1][1] = __builtin_amdgcn_mfma_f32_16x16x32_bf16(a01, b3, acc[0][1][1], 0, 0, 0);
            acc[1][0][1] = __builtin_amdgcn_mfma_f32_16x16x32_bf16(a10, b3, acc[1][0][1], 0, 0, 0);
            acc[1][1][1] = __builtin_amdgcn_mfma_f32_16x16x32_bf16(a11, b3, acc[1][1][1], 0, 0, 0);
        }

        // epilogue per tile: SwiGLU -> Ct -> one contiguous frag store per lane.
        // hgf frag slot = (G*8 + (cg>>1))*2 + sub ; within-frag lane offset:
        // q_glob = (cg&1)*2 + (q&1), elem = q_glob*128 + m16*8
#pragma unroll
        for (int t2 = 0; t2 < 2; ++t2) {
            if (t2 && !v1) break;
#pragma unroll
            for (int sub = 0; sub < 2; ++sub)
#pragma unroll
                for (int r = 0; r < 4; ++r) {
                    float g = acc[t2][sub][0][r];
                    float u = acc[t2][sub][1][r];
                    float hv = g / (1.f + __expf(-g)) * u;
                    Ct[w][sub][q * 4 + r][m16] = (short)f2bf(hv);
                }
            int sub = q >> 1;
            s16x8 hv8 = *(const s16x8*)&Ct[w][sub][m16][(q & 1) * 8];
            size_t slot = ((size_t)(G0 + T0 + t2) * 8 + (cg >> 1)) * 2 + sub;
            *(s16x8*)(hgf + slot * 512 + ((cg & 1) * 2 + (q & 1)) * 128 + m16 * 8) = hv8;
        }
    }
}

// ---------------- K2: y = H@W2 ------------------------------------------------
// Block = (expert, 32-col slice), 1024 blocks, 16 KB B-LDS, 2 tiles/wave-iter.
__global__ __launch_bounds__(256, 4) void gemm2_k(const short* __restrict__ hgf,
                                                  const float* __restrict__ w2,
                                                  const int* __restrict__ counts,
                                                  const int* __restrict__ etok,
                                                  const int* __restrict__ tbase,
                                                  short* __restrict__ ybuf)
{
    __shared__ short Bl[2][8][64][8];   // slice, kt2, flane, j = 16 KB

    int e  = blockIdx.x & 63, cg = blockIdx.x >> 6;   // cg 0..15 -> 32-col slice
    int n0 = cg * 32;
    int tid = threadIdx.x;
    int w = tid >> 6, lane = tid & 63;
    int q = lane >> 4, m16 = lane & 15;

    // ---- stage W2 slice: 1024 (row-pair, col-quad) items, 4/thread ----
    const float* W2e = w2 + (size_t)e * MOE * DIM + n0;
#pragma unroll
    for (int it = 0; it < 4; ++it) {
        int idx = it * 256 + tid;
        int r2  = idx >> 3;              // row pair 0..127
        int cq  = (idx & 7) * 4;         // col 0..28
        int k   = r2 * 2;
        int kt2 = k >> 5, qf = (k >> 3) & 3, j0 = k & 7;
        int s = cq >> 4, c15 = cq & 15;
        const float* p = W2e + (size_t)k * DIM + cq;
        float4 lo = *(const float4*)p;
        float4 hi = *(const float4*)(p + DIM);
        unsigned* b = (unsigned*)&Bl[s][kt2][qf * 16 + c15][j0];
        b[0]  = pk2(lo.x, hi.x);
        b[4]  = pk2(lo.y, hi.y);
        b[8]  = pk2(lo.z, hi.z);
        b[12] = pk2(lo.w, hi.w);
    }
    __syncthreads();

    int ne = min(counts[e], CAP);
    int nt = (ne + 31) >> 5;
    int G0 = tbase[e];
    const int* el = etok + e * CAP;

    for (int T0 = w * 2; T0 < nt; T0 += 8) {
        bool v1 = (T0 + 1) < nt;
        const short* A0 = hgf + (size_t)(G0 + T0) * 8192 + lane * 8;
        const short* A1 = hgf + (size_t)(G0 + (v1 ? T0 + 1 : T0)) * 8192 + lane * 8;

        f32x4 acc[2][2][2];   // [tile][sub][slice]
#pragma unroll
        for (int i = 0; i < 2; ++i)
#pragma unroll
            for (int j = 0; j < 2; ++j)
#pragma unroll
                for (int m = 0; m < 2; ++m) acc[i][j][m] = (f32x4)0.f;

#pragma unroll
        for (int kt = 0; kt < 8; ++kt) {
            s16x8 a00 = *(const s16x8*)(A0 + (size_t)(kt * 2 + 0) * 512);
            s16x8 a01 = *(const s16x8*)(A0 + (size_t)(kt * 2 + 1) * 512);
            s16x8 a10 = *(const s16x8*)(A1 + (size_t)(kt * 2 + 0) * 512);
            s16x8 a11 = *(const s16x8*)(A1 + (size_t)(kt * 2 + 1) * 512);
            s16x8 b0 = *(const s16x8*)&Bl[0][kt][lane][0];
            s16x8 b1 = *(const s16x8*)&Bl[1][kt][lane][0];
            acc[0][0][0] = __builtin_amdgcn_mfma_f32_16x16x32_bf16(a00, b0, acc[0][0][0], 0, 0, 0);
            acc[0][1][0] = __builtin_amdgcn_mfma_f32_16x16x32_bf16(a01, b0, acc[0][1][0], 0, 0, 0);
            acc[1][0][0] = __builtin_amdgcn_mfma_f32_16x16x32_bf16(a10, b0, acc[1][0][0], 0, 0, 0);
            acc[1][1][0] = __builtin_amdgcn_mfma_f32_16x16x32_bf16(a11, b0, acc[1][1][0], 0, 0, 0);
            acc[0][0][1] = __builtin_amdgcn_mfma_f32_16x16x32_bf16(a00, b1, acc[0][0][1], 0, 0, 0);
            acc[0][1][1] = __builtin_amdgcn_mfma_f32_16x16x32_bf16(a01, b1, acc[0][1][1], 0, 0, 0);
            acc[1][0][1] = __builtin_amdgcn_mfma_f32_16x16x32_bf16(a10, b1, acc[1][0][1], 0, 0, 0);
            acc[1][1][1] = __builtin_amdgcn_mfma_f32_16x16x32_bf16(a11, b1, acc[1][1][1], 0, 0, 0);
        }

#pragma unroll
        for (int t2 = 0; t2 < 2; ++t2) {
            if (t2 && !v1) break;
            int T = T0 + t2;
#pragma unroll
            for (int sub = 0; sub < 2; ++sub)
#pragma unroll
                for (int s = 0; s < 2; ++s)
#pragma unroll
                    for (int r = 0; r < 4; ++r) {
                        int row = T * 32 + sub * 16 + q * 4 + r;
                        if (row < ne)
                            ybuf[(size_t)el[row] * DIM + n0 + s * 16 + m16] =
                                (short)f2bf(acc[t2][sub][s][r]);
                    }
        }
    }
}

// ---------------- Combine -----------------------------------------------------
__global__ __launch_bounds__(256) void combine_k(const short* __restrict__ ybuf,
                                                 const float* __restrict__ wt_of,
                                                 float* __restrict__ out)
{
    int t = blockIdx.x;
    int tid = threadIdx.x;
    const int* yb = (const int*)ybuf;
    float sx = 0.f, sy = 0.f;
#pragma unroll
    for (int k = 0; k < TOPK; ++k) {
        float wk = wt_of[t * TOPK + k];
        int v = yb[(size_t)(t * TOPK + k) * (DIM / 2) + tid];
        float lo = __builtin_bit_cast(float, (unsigned)v << 16);
        float hi = __builtin_bit_cast(float, (unsigned)v & 0xffff0000u);
        sx += wk * lo;
        sy += wk * hi;
    }
    float2 o = {sx, sy};
    ((float2*)out)[(size_t)t * (DIM / 2) + tid] = o;
}

extern "C" void kernel_launch(void* const* d_in, const int* in_sizes, int n_in,
                              void* d_out, int out_size, void* d_ws, size_t ws_size,
                              hipStream_t stream)
{
    const float* x  = (const float*)d_in[0];
    const float* gw = (const float*)d_in[1];
    const float* gb = (const float*)d_in[2];
    const float* w1 = (const float*)d_in[3];
    const float* w3 = (const float*)d_in[4];
    const float* w2 = (const float*)d_in[5];

    char* ws = (char*)d_ws;
    short* xb    = (short*)(ws);                      //  2,097,152
    short* xgf   = (short*)(ws + 2097152);            // 576 tiles * 32 KB = 18,874,368
    short* hgf   = (short*)(ws + 20971520);           // 576 tiles * 16 KB =  9,437,184
    short* ybuf  = (short*)(ws + 30408704);           // 16,777,216
    float* gwT   = (float*)(ws + 47185920);           //    131,072
    int*   etok  = (int*)  (ws + 47316992);           //    262,144
    float* wt_of = (float*)(ws + 47579136);           //     65,536
    int*   counts= (int*)  (ws + 47644672);           //        256
    int*   tbase = (int*)  (ws + 47644928);           //        256

    hipMemsetAsync(counts, 0, NE * 4, stream);

    gwt_k<<<128, 256, 0, stream>>>(gw, gwT);
    gate_fused_k<<<T_TOK / 4, 256, 0, stream>>>(x, gwT, gb, counts, etok, wt_of, xb);
    scan_k<<<1, 64, 0, stream>>>(counts, tbase);
    gather_k<<<NE * 8, 256, 0, stream>>>(xb, counts, etok, tbase, xgf);
    gemm1_k<<<NE * 16, 256, 0, stream>>>(xgf, w1, w3, counts, tbase, hgf);
    gemm2_k<<<NE * 16, 256, 0, stream>>>(hgf, w2, counts, etok, tbase, ybuf);
    combine_k<<<T_TOK, 256, 0, stream>>>(ybuf, wt_of, (float*)d_out);
}

// Round 11
// 275.962 us; speedup vs baseline: 1.0177x; 1.0177x over previous
//
#include <hip/hip_runtime.h>

#define T_TOK 2048
#define DIM   512
#define MOE   256
#define NE    64
#define NG    8
#define TOPKG 4
#define TOPK  8
#define CAP   1024
#define MOE_SCALE 2.5f

typedef float f32x4 __attribute__((ext_vector_type(4)));
typedef short s16x8 __attribute__((ext_vector_type(8)));

__device__ __forceinline__ unsigned short f2bf(float f) {
    unsigned u = __builtin_bit_cast(unsigned, f);
    unsigned r = (u + 0x7fffu + ((u >> 16) & 1u)) >> 16;
    return (unsigned short)r;
}
__device__ __forceinline__ unsigned pk2(float lo, float hi) {
    return (unsigned)f2bf(lo) | ((unsigned)f2bf(hi) << 16);
}

// ---------------- gw transpose ------------------------------------------------
__global__ __launch_bounds__(256) void gwt_k(const float* __restrict__ gw,
                                             float* __restrict__ gwT)
{
    int idx = blockIdx.x * 256 + threadIdx.x;
    int e = idx >> 9, k = idx & 511;
    gwT[(size_t)(k >> 2) * 256 + e * 4 + (k & 3)] = gw[idx];
}

// ---------------- Fused gating + x->bf16, one wave per token ------------------
__global__ __launch_bounds__(256) void gate_fused_k(const float* __restrict__ x,
                                                    const float* __restrict__ gwT,
                                                    const float* __restrict__ gb,
                                                    int* __restrict__ counts,
                                                    int* __restrict__ etok,
                                                    float* __restrict__ wt_of,
                                                    short* __restrict__ xb)
{
    __shared__ float xs[4][512];
    int w = threadIdx.x >> 6, lane = threadIdx.x & 63;
    int t = blockIdx.x * 4 + w;

    {
        const float4* xr = (const float4*)(x + (size_t)t * DIM);
        float4 v0 = xr[lane * 2], v1 = xr[lane * 2 + 1];
        *(float4*)&xs[w][lane * 8]     = v0;
        *(float4*)&xs[w][lane * 8 + 4] = v1;
        short o[8];
        o[0] = (short)f2bf(v0.x); o[1] = (short)f2bf(v0.y);
        o[2] = (short)f2bf(v0.z); o[3] = (short)f2bf(v0.w);
        o[4] = (short)f2bf(v1.x); o[5] = (short)f2bf(v1.y);
        o[6] = (short)f2bf(v1.z); o[7] = (short)f2bf(v1.w);
        *(s16x8*)(xb + (size_t)t * DIM + lane * 8) = *(const s16x8*)o;
    }
    __syncthreads();

    const float4* gt = (const float4*)gwT;
    float a0 = 0.f, a1 = 0.f, a2 = 0.f, a3 = 0.f;
#pragma unroll 4
    for (int k4 = 0; k4 < 128; k4 += 4) {
        float4 g0 = gt[(k4 + 0) * 64 + lane];
        float4 g1 = gt[(k4 + 1) * 64 + lane];
        float4 g2 = gt[(k4 + 2) * 64 + lane];
        float4 g3 = gt[(k4 + 3) * 64 + lane];
        float4 x0 = *(const float4*)&xs[w][(k4 + 0) * 4];
        float4 x1 = *(const float4*)&xs[w][(k4 + 1) * 4];
        float4 x2 = *(const float4*)&xs[w][(k4 + 2) * 4];
        float4 x3 = *(const float4*)&xs[w][(k4 + 3) * 4];
        a0 += g0.x * x0.x + g0.y * x0.y + g0.z * x0.z + g0.w * x0.w;
        a1 += g1.x * x1.x + g1.y * x1.y + g1.z * x1.z + g1.w * x1.w;
        a2 += g2.x * x2.x + g2.y * x2.y + g2.z * x2.z + g2.w * x2.w;
        a3 += g3.x * x3.x + g3.y * x3.y + g3.z * x3.z + g3.w * x3.w;
    }
    float acc = (a0 + a1) + (a2 + a3);
    float sc = 1.f / (1.f + __expf(-acc));
    float s  = sc + gb[lane];

    float m1 = s, m2 = -1e30f;
#pragma unroll
    for (int d = 1; d < 8; d <<= 1) {
        float o1 = __shfl_xor(m1, d);
        float o2 = __shfl_xor(m2, d);
        float n1 = fmaxf(m1, o1);
        float n2 = fmaxf(fminf(m1, o1), fmaxf(m2, o2));
        m1 = n1; m2 = n2;
    }
    float gv = m1 + m2;

    bool gkeep = false;
#pragma unroll
    for (int it = 0; it < TOPKG; ++it) {
        float m = gv;
#pragma unroll
        for (int d = 1; d < 64; d <<= 1) m = fmaxf(m, __shfl_xor(m, d));
        unsigned long long mask = __ballot(gv == m);
        int ldr = __ffsll(mask) - 1;
        if ((lane >> 3) == (ldr >> 3)) { gkeep = true; gv = -2e30f; }
    }
    float sv = gkeep ? s : -1e30f;

    float wsum = 0.f;
    int my_e = 0; float my_w = 0.f;
#pragma unroll
    for (int k = 0; k < TOPK; ++k) {
        float m = sv;
#pragma unroll
        for (int d = 1; d < 64; d <<= 1) m = fmaxf(m, __shfl_xor(m, d));
        unsigned long long mask = __ballot(sv == m);
        int l = __ffsll(mask) - 1;
        float wk = __shfl(sc, l);
        wsum += wk;
        if (lane == k) { my_e = l; my_w = wk; }
        if (lane == l) sv = -2e30f;
    }
    float scale = MOE_SCALE / wsum;
    if (lane < TOPK) {
        int p = atomicAdd(&counts[my_e], 1);
        int rid = t * TOPK + lane;
        bool ok = (p < CAP);
        if (ok) etok[my_e * CAP + p] = rid;
        wt_of[rid] = ok ? my_w * scale : 0.f;
    }
}

// ---------------- scan: tile-base per expert (pad-to-32) ----------------------
__global__ __launch_bounds__(64) void scan_k(const int* __restrict__ counts,
                                             int* __restrict__ tbase)
{
    int lane = threadIdx.x;
    int ne = min(counts[lane], CAP);
    int nt = (ne + 31) >> 5;
    int v = nt;
#pragma unroll
    for (int d = 1; d < 64; d <<= 1) {
        int o = __shfl_up(v, d);
        if (lane >= d) v += o;
    }
    tbase[lane] = v - nt;
}

// ---------------- gather: tokens -> xg in A-frag-major layout -----------------
__global__ __launch_bounds__(256) void gather_k(const short* __restrict__ xb,
                                                const int* __restrict__ counts,
                                                const int* __restrict__ etok,
                                                const int* __restrict__ tbase,
                                                short* __restrict__ xgf)
{
    int e = blockIdx.x >> 3, sub3 = blockIdx.x & 7;
    int w = threadIdx.x >> 6, lane = threadIdx.x & 63;
    int T = sub3 * 4 + w;
    int ne = min(counts[e], CAP);
    int nt = (ne + 31) >> 5;
    if (T >= nt) return;
    int G = tbase[e] + T;
    int q = lane >> 4, m16 = lane & 15;
    int r0 = T * 32 + m16, r1 = T * 32 + 16 + m16;
    bool ok0 = r0 < ne, ok1 = r1 < ne;
    int tok0 = ok0 ? (etok[e * CAP + r0] >> 3) : 0;
    int tok1 = ok1 ? (etok[e * CAP + r1] >> 3) : 0;
    const short* s0 = xb + (size_t)tok0 * DIM + q * 8;
    const short* s1 = xb + (size_t)tok1 * DIM + q * 8;
    short* dst = xgf + (size_t)G * 16384 + lane * 8;
    s16x8 z = {0, 0, 0, 0, 0, 0, 0, 0};
#pragma unroll
    for (int b4 = 0; b4 < 4; ++b4) {
        s16x8 v[8];
#pragma unroll
        for (int i = 0; i < 4; ++i) {
            int kt = b4 * 4 + i;
            v[i * 2]     = ok0 ? *(const s16x8*)(s0 + kt * 32) : z;
            v[i * 2 + 1] = ok1 ? *(const s16x8*)(s1 + kt * 32) : z;
        }
#pragma unroll
        for (int i = 0; i < 4; ++i) {
            int kt = b4 * 4 + i;
            *(s16x8*)(dst + (size_t)(kt * 2 + 0) * 512) = v[i * 2];
            *(s16x8*)(dst + (size_t)(kt * 2 + 1) * 512) = v[i * 2 + 1];
        }
    }
}

// ---------------- K1: h = silu(X@W1)*(X@W3) ----------------------------------
// Block = (expert, 16-col slice), 1024 blocks, 32 KB B-LDS.
// launch_bounds(256,3): 170-VGPR budget -> no spill (r10's (256,4) spilled:
// WRITE 75 MB vs logical 8 MB), 3 blocks/CU = 12 waves/CU.
__global__ __launch_bounds__(256, 3) void gemm1_k(const short* __restrict__ xgf,
                                                  const float* __restrict__ w1,
                                                  const float* __restrict__ w3,
                                                  const int* __restrict__ counts,
                                                  const int* __restrict__ tbase,
                                                  short* __restrict__ hgf)
{
    __shared__ short Bl[2][16][64][8];       // mat, kt, flane, j = 32 KB
    __shared__ short Ct[4][2][16][24];       // wave, sub, row, col(+pad) = 6 KB

    int e  = blockIdx.x & 63, cg = blockIdx.x >> 6;   // cg 0..15 -> 16-col slice
    int n0 = cg * 16;
    int tid = threadIdx.x;
    int w = tid >> 6, lane = tid & 63;
    int q = lane >> 4, m16 = lane & 15;

    const float* W1e = w1 + (size_t)e * DIM * MOE + n0;
    const float* W3e = w3 + (size_t)e * DIM * MOE + n0;
#pragma unroll
    for (int it = 0; it < 8; ++it) {
        int idx = it * 256 + tid;
        int mat = idx >> 10;
        int rem = idx & 1023;
        int r2  = rem >> 2;              // row pair 0..255
        int cq  = (rem & 3) * 4;         // col 0,4,8,12
        int k   = r2 * 2;
        int kt = k >> 5, qf = (k >> 3) & 3, j0 = k & 7;
        const float* p = (mat ? W3e : W1e) + (size_t)k * MOE + cq;
        float4 lo = *(const float4*)p;
        float4 hi = *(const float4*)(p + MOE);
        unsigned* b = (unsigned*)&Bl[mat][kt][qf * 16 + cq][j0];
        b[0]  = pk2(lo.x, hi.x);
        b[4]  = pk2(lo.y, hi.y);
        b[8]  = pk2(lo.z, hi.z);
        b[12] = pk2(lo.w, hi.w);
    }
    __syncthreads();

    int ne = min(counts[e], CAP);
    int nt = (ne + 31) >> 5;
    int G0 = tbase[e];

    for (int T0 = w * 2; T0 < nt; T0 += 8) {
        bool v1 = (T0 + 1) < nt;
        const short* A0 = xgf + (size_t)(G0 + T0) * 16384 + lane * 8;
        const short* A1 = xgf + (size_t)(G0 + (v1 ? T0 + 1 : T0)) * 16384 + lane * 8;

        f32x4 acc[2][2][2];   // [tile][sub][mat]
#pragma unroll
        for (int i = 0; i < 2; ++i)
#pragma unroll
            for (int j = 0; j < 2; ++j)
#pragma unroll
                for (int m = 0; m < 2; ++m) acc[i][j][m] = (f32x4)0.f;

#pragma unroll
        for (int kt = 0; kt < 16; ++kt) {
            s16x8 a00 = *(const s16x8*)(A0 + (size_t)(kt * 2 + 0) * 512);
            s16x8 a01 = *(const s16x8*)(A0 + (size_t)(kt * 2 + 1) * 512);
            s16x8 a10 = *(const s16x8*)(A1 + (size_t)(kt * 2 + 0) * 512);
            s16x8 a11 = *(const s16x8*)(A1 + (size_t)(kt * 2 + 1) * 512);
            s16x8 b1 = *(const s16x8*)&Bl[0][kt][lane][0];
            s16x8 b3 = *(const s16x8*)&Bl[1][kt][lane][0];
            acc[0][0][0] = __builtin_amdgcn_mfma_f32_16x16x32_bf16(a00, b1, acc[0][0][0], 0, 0, 0);
            acc[0][1][0] = __builtin_amdgcn_mfma_f32_16x16x32_bf16(a01, b1, acc[0][1][0], 0, 0, 0);
            acc[1][0][0] = __builtin_amdgcn_mfma_f32_16x16x32_bf16(a10, b1, acc[1][0][0], 0, 0, 0);
            acc[1][1][0] = __builtin_amdgcn_mfma_f32_16x16x32_bf16(a11, b1, acc[1][1][0], 0, 0, 0);
            acc[0][0][1] = __builtin_amdgcn_mfma_f32_16x16x32_bf16(a00, b3, acc[0][0][1], 0, 0, 0);
            acc[0][1][1] = __builtin_amdgcn_mfma_f32_16x16x32_bf16(a01, b3, acc[0][1][1], 0, 0, 0);
            acc[1][0][1] = __builtin_amdgcn_mfma_f32_16x16x32_bf16(a10, b3, acc[1][0][1], 0, 0, 0);
            acc[1][1][1] = __builtin_amdgcn_mfma_f32_16x16x32_bf16(a11, b3, acc[1][1][1], 0, 0, 0);
        }

#pragma unroll
        for (int t2 = 0; t2 < 2; ++t2) {
            if (t2 && !v1) break;
#pragma unroll
            for (int sub = 0; sub < 2; ++sub)
#pragma unroll
                for (int r = 0; r < 4; ++r) {
                    float g = acc[t2][sub][0][r];
                    float u = acc[t2][sub][1][r];
                    float hv = g / (1.f + __expf(-g)) * u;
                    Ct[w][sub][q * 4 + r][m16] = (short)f2bf(hv);
                }
            int sub = q >> 1;
            s16x8 hv8 = *(const s16x8*)&Ct[w][sub][m16][(q & 1) * 8];
            size_t slot = ((size_t)(G0 + T0 + t2) * 8 + (cg >> 1)) * 2 + sub;
            *(s16x8*)(hgf + slot * 512 + ((cg & 1) * 2 + (q & 1)) * 128 + m16 * 8) = hv8;
        }
    }
}

// ---------------- K2: y = H@W2 ------------------------------------------------
__global__ __launch_bounds__(256, 3) void gemm2_k(const short* __restrict__ hgf,
                                                  const float* __restrict__ w2,
                                                  const int* __restrict__ counts,
                                                  const int* __restrict__ etok,
                                                  const int* __restrict__ tbase,
                                                  short* __restrict__ ybuf)
{
    __shared__ short Bl[2][8][64][8];   // slice, kt2, flane, j = 16 KB

    int e  = blockIdx.x & 63, cg = blockIdx.x >> 6;   // cg 0..15 -> 32-col slice
    int n0 = cg * 32;
    int tid = threadIdx.x;
    int w = tid >> 6, lane = tid & 63;
    int q = lane >> 4, m16 = lane & 15;

    const float* W2e = w2 + (size_t)e * MOE * DIM + n0;
#pragma unroll
    for (int it = 0; it < 4; ++it) {
        int idx = it * 256 + tid;
        int r2  = idx >> 3;
        int cq  = (idx & 7) * 4;
        int k   = r2 * 2;
        int kt2 = k >> 5, qf = (k >> 3) & 3, j0 = k & 7;
        int s = cq >> 4, c15 = cq & 15;
        const float* p = W2e + (size_t)k * DIM + cq;
        float4 lo = *(const float4*)p;
        float4 hi = *(const float4*)(p + DIM);
        unsigned* b = (unsigned*)&Bl[s][kt2][qf * 16 + c15][j0];
        b[0]  = pk2(lo.x, hi.x);
        b[4]  = pk2(lo.y, hi.y);
        b[8]  = pk2(lo.z, hi.z);
        b[12] = pk2(lo.w, hi.w);
    }
    __syncthreads();

    int ne = min(counts[e], CAP);
    int nt = (ne + 31) >> 5;
    int G0 = tbase[e];
    const int* el = etok + e * CAP;

    for (int T0 = w * 2; T0 < nt; T0 += 8) {
        bool v1 = (T0 + 1) < nt;
        const short* A0 = hgf + (size_t)(G0 + T0) * 8192 + lane * 8;
        const short* A1 = hgf + (size_t)(G0 + (v1 ? T0 + 1 : T0)) * 8192 + lane * 8;

        f32x4 acc[2][2][2];   // [tile][sub][slice]
#pragma unroll
        for (int i = 0; i < 2; ++i)
#pragma unroll
            for (int j = 0; j < 2; ++j)
#pragma unroll
                for (int m = 0; m < 2; ++m) acc[i][j][m] = (f32x4)0.f;

#pragma unroll
        for (int kt = 0; kt < 8; ++kt) {
            s16x8 a00 = *(const s16x8*)(A0 + (size_t)(kt * 2 + 0) * 512);
            s16x8 a01 = *(const s16x8*)(A0 + (size_t)(kt * 2 + 1) * 512);
            s16x8 a10 = *(const s16x8*)(A1 + (size_t)(kt * 2 + 0) * 512);
            s16x8 a11 = *(const s16x8*)(A1 + (size_t)(kt * 2 + 1) * 512);
            s16x8 b0 = *(const s16x8*)&Bl[0][kt][lane][0];
            s16x8 b1 = *(const s16x8*)&Bl[1][kt][lane][0];
            acc[0][0][0] = __builtin_amdgcn_mfma_f32_16x16x32_bf16(a00, b0, acc[0][0][0], 0, 0, 0);
            acc[0][1][0] = __builtin_amdgcn_mfma_f32_16x16x32_bf16(a01, b0, acc[0][1][0], 0, 0, 0);
            acc[1][0][0] = __builtin_amdgcn_mfma_f32_16x16x32_bf16(a10, b0, acc[1][0][0], 0, 0, 0);
            acc[1][1][0] = __builtin_amdgcn_mfma_f32_16x16x32_bf16(a11, b0, acc[1][1][0], 0, 0, 0);
            acc[0][0][1] = __builtin_amdgcn_mfma_f32_16x16x32_bf16(a00, b1, acc[0][0][1], 0, 0, 0);
            acc[0][1][1] = __builtin_amdgcn_mfma_f32_16x16x32_bf16(a01, b1, acc[0][1][1], 0, 0, 0);
            acc[1][0][1] = __builtin_amdgcn_mfma_f32_16x16x32_bf16(a10, b1, acc[1][0][1], 0, 0, 0);
            acc[1][1][1] = __builtin_amdgcn_mfma_f32_16x16x32_bf16(a11, b1, acc[1][1][1], 0, 0, 0);
        }

#pragma unroll
        for (int t2 = 0; t2 < 2; ++t2) {
            if (t2 && !v1) break;
            int T = T0 + t2;
#pragma unroll
            for (int sub = 0; sub < 2; ++sub)
#pragma unroll
                for (int s = 0; s < 2; ++s)
#pragma unroll
                    for (int r = 0; r < 4; ++r) {
                        int row = T * 32 + sub * 16 + q * 4 + r;
                        if (row < ne)
                            ybuf[(size_t)el[row] * DIM + n0 + s * 16 + m16] =
                                (short)f2bf(acc[t2][sub][s][r]);
                    }
        }
    }
}

// ---------------- Combine -----------------------------------------------------
__global__ __launch_bounds__(256) void combine_k(const short* __restrict__ ybuf,
                                                 const float* __restrict__ wt_of,
                                                 float* __restrict__ out)
{
    int t = blockIdx.x;
    int tid = threadIdx.x;
    const int* yb = (const int*)ybuf;
    float sx = 0.f, sy = 0.f;
#pragma unroll
    for (int k = 0; k < TOPK; ++k) {
        float wk = wt_of[t * TOPK + k];
        int v = yb[(size_t)(t * TOPK + k) * (DIM / 2) + tid];
        float lo = __builtin_bit_cast(float, (unsigned)v << 16);
        float hi = __builtin_bit_cast(float, (unsigned)v & 0xffff0000u);
        sx += wk * lo;
        sy += wk * hi;
    }
    float2 o = {sx, sy};
    ((float2*)out)[(size_t)t * (DIM / 2) + tid] = o;
}

extern "C" void kernel_launch(void* const* d_in, const int* in_sizes, int n_in,
                              void* d_out, int out_size, void* d_ws, size_t ws_size,
                              hipStream_t stream)
{
    const float* x  = (const float*)d_in[0];
    const float* gw = (const float*)d_in[1];
    const float* gb = (const float*)d_in[2];
    const float* w1 = (const float*)d_in[3];
    const float* w3 = (const float*)d_in[4];
    const float* w2 = (const float*)d_in[5];

    char* ws = (char*)d_ws;
    short* xb    = (short*)(ws);                      //  2,097,152
    short* xgf   = (short*)(ws + 2097152);            // 576 tiles * 32 KB = 18,874,368
    short* hgf   = (short*)(ws + 20971520);           // 576 tiles * 16 KB =  9,437,184
    short* ybuf  = (short*)(ws + 30408704);           // 16,777,216
    float* gwT   = (float*)(ws + 47185920);           //    131,072
    int*   etok  = (int*)  (ws + 47316992);           //    262,144
    float* wt_of = (float*)(ws + 47579136);           //     65,536
    int*   counts= (int*)  (ws + 47644672);           //        256
    int*   tbase = (int*)  (ws + 47644928);           //        256

    hipMemsetAsync(counts, 0, NE * 4, stream);

    gwt_k<<<128, 256, 0, stream>>>(gw, gwT);
    gate_fused_k<<<T_TOK / 4, 256, 0, stream>>>(x, gwT, gb, counts, etok, wt_of, xb);
    scan_k<<<1, 64, 0, stream>>>(counts, tbase);
    gather_k<<<NE * 8, 256, 0, stream>>>(xb, counts, etok, tbase, xgf);
    gemm1_k<<<NE * 16, 256, 0, stream>>>(xgf, w1, w3, counts, tbase, hgf);
    gemm2_k<<<NE * 16, 256, 0, stream>>>(hgf, w2, counts, etok, tbase, ybuf);
    combine_k<<<T_TOK, 256, 0, stream>>>(ybuf, wt_of, (float*)d_out);
}

// Round 12
// 249.462 us; speedup vs baseline: 1.1258x; 1.1062x over previous
//
#include <hip/hip_runtime.h>

#define T_TOK 2048
#define DIM   512
#define MOE   256
#define NE    64
#define NG    8
#define TOPKG 4
#define TOPK  8
#define CAP   1024
#define MOE_SCALE 2.5f

typedef float f32x4 __attribute__((ext_vector_type(4)));
typedef short s16x8 __attribute__((ext_vector_type(8)));

__device__ __forceinline__ unsigned short f2bf(float f) {
    unsigned u = __builtin_bit_cast(unsigned, f);
    unsigned r = (u + 0x7fffu + ((u >> 16) & 1u)) >> 16;
    return (unsigned short)r;
}
__device__ __forceinline__ unsigned pk2(float lo, float hi) {
    return (unsigned)f2bf(lo) | ((unsigned)f2bf(hi) << 16);
}

// ---------------- gw transpose ------------------------------------------------
__global__ __launch_bounds__(256) void gwt_k(const float* __restrict__ gw,
                                             float* __restrict__ gwT)
{
    int idx = blockIdx.x * 256 + threadIdx.x;
    int e = idx >> 9, k = idx & 511;
    gwT[(size_t)(k >> 2) * 256 + e * 4 + (k & 3)] = gw[idx];
}

// ---------------- Fused gating + x->bf16, one wave per token ------------------
__global__ __launch_bounds__(256) void gate_fused_k(const float* __restrict__ x,
                                                    const float* __restrict__ gwT,
                                                    const float* __restrict__ gb,
                                                    int* __restrict__ counts,
                                                    int* __restrict__ etok,
                                                    float* __restrict__ wt_of,
                                                    short* __restrict__ xb)
{
    __shared__ float xs[4][512];
    int w = threadIdx.x >> 6, lane = threadIdx.x & 63;
    int t = blockIdx.x * 4 + w;

    {
        const float4* xr = (const float4*)(x + (size_t)t * DIM);
        float4 v0 = xr[lane * 2], v1 = xr[lane * 2 + 1];
        *(float4*)&xs[w][lane * 8]     = v0;
        *(float4*)&xs[w][lane * 8 + 4] = v1;
        short o[8];
        o[0] = (short)f2bf(v0.x); o[1] = (short)f2bf(v0.y);
        o[2] = (short)f2bf(v0.z); o[3] = (short)f2bf(v0.w);
        o[4] = (short)f2bf(v1.x); o[5] = (short)f2bf(v1.y);
        o[6] = (short)f2bf(v1.z); o[7] = (short)f2bf(v1.w);
        *(s16x8*)(xb + (size_t)t * DIM + lane * 8) = *(const s16x8*)o;
    }
    __syncthreads();

    const float4* gt = (const float4*)gwT;
    float a0 = 0.f, a1 = 0.f, a2 = 0.f, a3 = 0.f;
#pragma unroll 4
    for (int k4 = 0; k4 < 128; k4 += 4) {
        float4 g0 = gt[(k4 + 0) * 64 + lane];
        float4 g1 = gt[(k4 + 1) * 64 + lane];
        float4 g2 = gt[(k4 + 2) * 64 + lane];
        float4 g3 = gt[(k4 + 3) * 64 + lane];
        float4 x0 = *(const float4*)&xs[w][(k4 + 0) * 4];
        float4 x1 = *(const float4*)&xs[w][(k4 + 1) * 4];
        float4 x2 = *(const float4*)&xs[w][(k4 + 2) * 4];
        float4 x3 = *(const float4*)&xs[w][(k4 + 3) * 4];
        a0 += g0.x * x0.x + g0.y * x0.y + g0.z * x0.z + g0.w * x0.w;
        a1 += g1.x * x1.x + g1.y * x1.y + g1.z * x1.z + g1.w * x1.w;
        a2 += g2.x * x2.x + g2.y * x2.y + g2.z * x2.z + g2.w * x2.w;
        a3 += g3.x * x3.x + g3.y * x3.y + g3.z * x3.z + g3.w * x3.w;
    }
    float acc = (a0 + a1) + (a2 + a3);
    float sc = 1.f / (1.f + __expf(-acc));
    float s  = sc + gb[lane];

    float m1 = s, m2 = -1e30f;
#pragma unroll
    for (int d = 1; d < 8; d <<= 1) {
        float o1 = __shfl_xor(m1, d);
        float o2 = __shfl_xor(m2, d);
        float n1 = fmaxf(m1, o1);
        float n2 = fmaxf(fminf(m1, o1), fmaxf(m2, o2));
        m1 = n1; m2 = n2;
    }
    float gv = m1 + m2;

    bool gkeep = false;
#pragma unroll
    for (int it = 0; it < TOPKG; ++it) {
        float m = gv;
#pragma unroll
        for (int d = 1; d < 64; d <<= 1) m = fmaxf(m, __shfl_xor(m, d));
        unsigned long long mask = __ballot(gv == m);
        int ldr = __ffsll(mask) - 1;
        if ((lane >> 3) == (ldr >> 3)) { gkeep = true; gv = -2e30f; }
    }
    float sv = gkeep ? s : -1e30f;

    float wsum = 0.f;
    int my_e = 0; float my_w = 0.f;
#pragma unroll
    for (int k = 0; k < TOPK; ++k) {
        float m = sv;
#pragma unroll
        for (int d = 1; d < 64; d <<= 1) m = fmaxf(m, __shfl_xor(m, d));
        unsigned long long mask = __ballot(sv == m);
        int l = __ffsll(mask) - 1;
        float wk = __shfl(sc, l);
        wsum += wk;
        if (lane == k) { my_e = l; my_w = wk; }
        if (lane == l) sv = -2e30f;
    }
    float scale = MOE_SCALE / wsum;
    if (lane < TOPK) {
        int p = atomicAdd(&counts[my_e], 1);
        int rid = t * TOPK + lane;
        bool ok = (p < CAP);
        if (ok) etok[my_e * CAP + p] = rid;
        wt_of[rid] = ok ? my_w * scale : 0.f;
    }
}

// ---------------- scan: tile-base per expert (pad-to-32) ----------------------
__global__ __launch_bounds__(64) void scan_k(const int* __restrict__ counts,
                                             int* __restrict__ tbase)
{
    int lane = threadIdx.x;
    int ne = min(counts[lane], CAP);
    int nt = (ne + 31) >> 5;
    int v = nt;
#pragma unroll
    for (int d = 1; d < 64; d <<= 1) {
        int o = __shfl_up(v, d);
        if (lane >= d) v += o;
    }
    tbase[lane] = v - nt;
}

// ---------------- K1: h = silu(X@W1)*(X@W3), A gathered from xb ---------------
// Block = (expert, 16-col slice), 1024 blocks, 32 KB B-LDS. 1 tile/wave-iter
// with explicit kt+1 A-prefetch (4 A-frags in flight); acc = 16 regs -> fits
// 85V/85A budget of (256,3) with NO spill (r11's 2-tile spilled 26 MB).
__global__ __launch_bounds__(256, 3) void gemm1_k(const short* __restrict__ xb,
                                                  const float* __restrict__ w1,
                                                  const float* __restrict__ w3,
                                                  const int* __restrict__ counts,
                                                  const int* __restrict__ etok,
                                                  const int* __restrict__ tbase,
                                                  short* __restrict__ hgf)
{
    __shared__ short Bl[2][16][64][8];       // mat, kt, flane, j = 32 KB
    __shared__ short Ct[4][2][16][24];       // wave, sub, row, col(+pad) = 6 KB

    int e  = blockIdx.x & 63, cg = blockIdx.x >> 6;   // cg 0..15 -> 16-col slice
    int n0 = cg * 16;
    int tid = threadIdx.x;
    int w = tid >> 6, lane = tid & 63;
    int q = lane >> 4, m16 = lane & 15;

    const float* W1e = w1 + (size_t)e * DIM * MOE + n0;
    const float* W3e = w3 + (size_t)e * DIM * MOE + n0;
#pragma unroll 4
    for (int it = 0; it < 8; ++it) {
        int idx = it * 256 + tid;
        int mat = idx >> 10;
        int rem = idx & 1023;
        int r2  = rem >> 2;              // row pair 0..255
        int cq  = (rem & 3) * 4;         // col 0,4,8,12
        int k   = r2 * 2;
        int kt = k >> 5, qf = (k >> 3) & 3, j0 = k & 7;
        const float* p = (mat ? W3e : W1e) + (size_t)k * MOE + cq;
        float4 lo = *(const float4*)p;
        float4 hi = *(const float4*)(p + MOE);
        unsigned* b = (unsigned*)&Bl[mat][kt][qf * 16 + cq][j0];
        b[0]  = pk2(lo.x, hi.x);
        b[4]  = pk2(lo.y, hi.y);
        b[8]  = pk2(lo.z, hi.z);
        b[12] = pk2(lo.w, hi.w);
    }
    __syncthreads();

    int ne = min(counts[e], CAP);
    int nt = (ne + 31) >> 5;
    int G0 = tbase[e];
    const int* el = etok + e * CAP;

    for (int T = w; T < nt; T += 4) {
        int row0 = T * 32 + m16, row1 = T * 32 + 16 + m16;
        int tok0 = el[row0 < ne ? row0 : ne - 1] >> 3;
        int tok1 = el[row1 < ne ? row1 : ne - 1] >> 3;
        const short* A0 = xb + (size_t)tok0 * DIM + q * 8;
        const short* A1 = xb + (size_t)tok1 * DIM + q * 8;

        f32x4 acc[2][2];   // [sub][mat]
#pragma unroll
        for (int j = 0; j < 2; ++j)
#pragma unroll
            for (int m = 0; m < 2; ++m) acc[j][m] = (f32x4)0.f;

        // software-pipelined K loop: prefetch kt+1 A-frags while MFMAing kt
        s16x8 a0 = *(const s16x8*)(A0);
        s16x8 a1 = *(const s16x8*)(A1);
#pragma unroll
        for (int kt = 0; kt < 16; ++kt) {
            s16x8 a0n, a1n;
            if (kt < 15) {
                a0n = *(const s16x8*)(A0 + (kt + 1) * 32);
                a1n = *(const s16x8*)(A1 + (kt + 1) * 32);
            }
            s16x8 b1 = *(const s16x8*)&Bl[0][kt][lane][0];
            s16x8 b3 = *(const s16x8*)&Bl[1][kt][lane][0];
            acc[0][0] = __builtin_amdgcn_mfma_f32_16x16x32_bf16(a0, b1, acc[0][0], 0, 0, 0);
            acc[1][0] = __builtin_amdgcn_mfma_f32_16x16x32_bf16(a1, b1, acc[1][0], 0, 0, 0);
            acc[0][1] = __builtin_amdgcn_mfma_f32_16x16x32_bf16(a0, b3, acc[0][1], 0, 0, 0);
            acc[1][1] = __builtin_amdgcn_mfma_f32_16x16x32_bf16(a1, b3, acc[1][1], 0, 0, 0);
            a0 = a0n; a1 = a1n;
        }

        // epilogue: SwiGLU -> Ct (per-wave) -> contiguous frag store to hgf
#pragma unroll
        for (int sub = 0; sub < 2; ++sub)
#pragma unroll
            for (int r = 0; r < 4; ++r) {
                float g = acc[sub][0][r];
                float u = acc[sub][1][r];
                float hv = g / (1.f + __expf(-g)) * u;
                Ct[w][sub][q * 4 + r][m16] = (short)f2bf(hv);
            }
        int sub = q >> 1;
        s16x8 hv8 = *(const s16x8*)&Ct[w][sub][m16][(q & 1) * 8];
        size_t slot = ((size_t)(G0 + T) * 8 + (cg >> 1)) * 2 + sub;
        *(s16x8*)(hgf + slot * 512 + ((cg & 1) * 2 + (q & 1)) * 128 + m16 * 8) = hv8;
    }
}

// ---------------- K2: y = H@W2 ------------------------------------------------
__global__ __launch_bounds__(256, 3) void gemm2_k(const short* __restrict__ hgf,
                                                  const float* __restrict__ w2,
                                                  const int* __restrict__ counts,
                                                  const int* __restrict__ etok,
                                                  const int* __restrict__ tbase,
                                                  short* __restrict__ ybuf)
{
    __shared__ short Bl[2][8][64][8];   // slice, kt2, flane, j = 16 KB

    int e  = blockIdx.x & 63, cg = blockIdx.x >> 6;   // cg 0..15 -> 32-col slice
    int n0 = cg * 32;
    int tid = threadIdx.x;
    int w = tid >> 6, lane = tid & 63;
    int q = lane >> 4, m16 = lane & 15;

    const float* W2e = w2 + (size_t)e * MOE * DIM + n0;
#pragma unroll 4
    for (int it = 0; it < 4; ++it) {
        int idx = it * 256 + tid;
        int r2  = idx >> 3;
        int cq  = (idx & 7) * 4;
        int k   = r2 * 2;
        int kt2 = k >> 5, qf = (k >> 3) & 3, j0 = k & 7;
        int s = cq >> 4, c15 = cq & 15;
        const float* p = W2e + (size_t)k * DIM + cq;
        float4 lo = *(const float4*)p;
        float4 hi = *(const float4*)(p + DIM);
        unsigned* b = (unsigned*)&Bl[s][kt2][qf * 16 + c15][j0];
        b[0]  = pk2(lo.x, hi.x);
        b[4]  = pk2(lo.y, hi.y);
        b[8]  = pk2(lo.z, hi.z);
        b[12] = pk2(lo.w, hi.w);
    }
    __syncthreads();

    int ne = min(counts[e], CAP);
    int nt = (ne + 31) >> 5;
    int G0 = tbase[e];
    const int* el = etok + e * CAP;

    for (int T = w; T < nt; T += 4) {
        const short* A = hgf + (size_t)(G0 + T) * 8192 + lane * 8;

        f32x4 acc[2][2];   // [sub][slice]
#pragma unroll
        for (int j = 0; j < 2; ++j)
#pragma unroll
            for (int m = 0; m < 2; ++m) acc[j][m] = (f32x4)0.f;

        s16x8 a0 = *(const s16x8*)(A);
        s16x8 a1 = *(const s16x8*)(A + 512);
#pragma unroll
        for (int kt = 0; kt < 8; ++kt) {
            s16x8 a0n, a1n;
            if (kt < 7) {
                a0n = *(const s16x8*)(A + (size_t)((kt + 1) * 2 + 0) * 512);
                a1n = *(const s16x8*)(A + (size_t)((kt + 1) * 2 + 1) * 512);
            }
            s16x8 b0 = *(const s16x8*)&Bl[0][kt][lane][0];
            s16x8 b1 = *(const s16x8*)&Bl[1][kt][lane][0];
            acc[0][0] = __builtin_amdgcn_mfma_f32_16x16x32_bf16(a0, b0, acc[0][0], 0, 0, 0);
            acc[1][0] = __builtin_amdgcn_mfma_f32_16x16x32_bf16(a1, b0, acc[1][0], 0, 0, 0);
            acc[0][1] = __builtin_amdgcn_mfma_f32_16x16x32_bf16(a0, b1, acc[0][1], 0, 0, 0);
            acc[1][1] = __builtin_amdgcn_mfma_f32_16x16x32_bf16(a1, b1, acc[1][1], 0, 0, 0);
            a0 = a0n; a1 = a1n;
        }

#pragma unroll
        for (int sub = 0; sub < 2; ++sub)
#pragma unroll
            for (int s = 0; s < 2; ++s)
#pragma unroll
                for (int r = 0; r < 4; ++r) {
                    int row = T * 32 + sub * 16 + q * 4 + r;
                    if (row < ne)
                        ybuf[(size_t)el[row] * DIM + n0 + s * 16 + m16] =
                            (short)f2bf(acc[sub][s][r]);
                }
    }
}

// ---------------- Combine -----------------------------------------------------
__global__ __launch_bounds__(256) void combine_k(const short* __restrict__ ybuf,
                                                 const float* __restrict__ wt_of,
                                                 float* __restrict__ out)
{
    int t = blockIdx.x;
    int tid = threadIdx.x;
    const int* yb = (const int*)ybuf;
    float sx = 0.f, sy = 0.f;
#pragma unroll
    for (int k = 0; k < TOPK; ++k) {
        float wk = wt_of[t * TOPK + k];
        int v = yb[(size_t)(t * TOPK + k) * (DIM / 2) + tid];
        float lo = __builtin_bit_cast(float, (unsigned)v << 16);
        float hi = __builtin_bit_cast(float, (unsigned)v & 0xffff0000u);
        sx += wk * lo;
        sy += wk * hi;
    }
    float2 o = {sx, sy};
    ((float2*)out)[(size_t)t * (DIM / 2) + tid] = o;
}

extern "C" void kernel_launch(void* const* d_in, const int* in_sizes, int n_in,
                              void* d_out, int out_size, void* d_ws, size_t ws_size,
                              hipStream_t stream)
{
    const float* x  = (const float*)d_in[0];
    const float* gw = (const float*)d_in[1];
    const float* gb = (const float*)d_in[2];
    const float* w1 = (const float*)d_in[3];
    const float* w3 = (const float*)d_in[4];
    const float* w2 = (const float*)d_in[5];

    char* ws = (char*)d_ws;
    short* xb    = (short*)(ws);                      //  2,097,152
    short* hgf   = (short*)(ws + 2097152);            // 576 tiles * 16 KB = 9,437,184
    short* ybuf  = (short*)(ws + 11534336);           // 16,777,216
    float* gwT   = (float*)(ws + 28311552);           //    131,072
    int*   etok  = (int*)  (ws + 28442624);           //    262,144
    float* wt_of = (float*)(ws + 28704768);           //     65,536
    int*   counts= (int*)  (ws + 28770304);           //        256
    int*   tbase = (int*)  (ws + 28770560);           //        256

    hipMemsetAsync(counts, 0, NE * 4, stream);

    gwt_k<<<128, 256, 0, stream>>>(gw, gwT);
    gate_fused_k<<<T_TOK / 4, 256, 0, stream>>>(x, gwT, gb, counts, etok, wt_of, xb);
    scan_k<<<1, 64, 0, stream>>>(counts, tbase);
    gemm1_k<<<NE * 16, 256, 0, stream>>>(xb, w1, w3, counts, etok, tbase, hgf);
    gemm2_k<<<NE * 16, 256, 0, stream>>>(hgf, w2, counts, etok, tbase, ybuf);
    combine_k<<<T_TOK, 256, 0, stream>>>(ybuf, wt_of, (float*)d_out);
}